// Round 4
// baseline (1174.273 us; speedup 1.0000x reference)
//
#include <hip/hip_runtime.h>
#include <hip/hip_bf16.h>
#include <math.h>

// SNN forward: 64 -> 1024 -> 1024 -> 10, T=4000, B=16, LIF beta=exp(-0.025),
// thr=1, hard reset to 0, Dale clamp W>=0.
// Layer-phased: per time-chunk, GEMM (spikes @ W bf16-limbs, fp32 acc) ->
// LIF scan (fp64 membranes). Spikes as bf16 {0,1}.
// BT is limb-interleaved ([hi64|lo64] per source k-block) so each A k-tile
// serves two consecutive GEMM k-iterations.
// k_scan_out uses LDS double-buffered global_load_lds prefetch (R3 showed the
// register-prefetch version gets collapsed by the compiler -> 546 cy/step).

#define T_STEPS 4000
#define NB 16
#define N_IN 64
#define NH 1024
#define N_OUT 10
#define SEG 50            // scan_out LDS segment: 2 x 50 x 1KB = 100 KB LDS

typedef __attribute__((ext_vector_type(8))) short bf16x8;
typedef __attribute__((ext_vector_type(4))) float f32x4;
typedef __hip_bfloat16 bf16;

#define ASG(p) (const __attribute__((address_space(1))) void*)(p)
#define ASL(p) (__attribute__((address_space(3))) void*)(p)

// ---------------- small utility kernels ----------------

__global__ void k_zero(double* p, int n) {
    int i = blockIdx.x * 256 + threadIdx.x;
    if (i < n) p[i] = 0.0;
}

__global__ void k_cvt(const float* __restrict__ in, bf16* __restrict__ out, int n) {
    int i = blockIdx.x * 256 + threadIdx.x;
    if (i < n) out[i] = __float2bfloat16(in[i]);   // 0.0/1.0 -> exact
}

// Build BT[n][k2] (row-major [Npad x 2K]) from W [K x N] row-major.
// Limb-interleaved K2: k2 -> kt2 = k2>>6, kk = k2&63; limb = kt2&1,
// source k = (kt2>>1)*64 + kk. limb0 = hi(max(W,0)), limb1 = w - hi.
__global__ void k_limbs(const float* __restrict__ W, bf16* __restrict__ BT,
                        int K, int N, int Npad) {
    int idx = blockIdx.x * 256 + threadIdx.x;
    int total = Npad * 2 * K;
    if (idx >= total) return;
    int n  = idx / (2 * K);
    int k2 = idx - n * (2 * K);
    int kt2 = k2 >> 6;
    int kk  = k2 & 63;
    int k   = ((kt2 >> 1) << 6) + kk;
    float v = 0.f;
    if (n < N) {
        float w = fmaxf(W[(size_t)k * N + n], 0.f);      // Dale's law clamp
        float hi = __bfloat162float(__float2bfloat16(w));
        v = ((kt2 & 1) == 0) ? w : (w - hi);
    }
    BT[idx] = __float2bfloat16(v);
}

// ---------------- GEMM: C[M x ldc] = A[M x KA] @ BT^T, bf16 in, f32 out ----
// BT is [Npad x K2], limb-interleaved: k-iteration kt uses A k-tile (kt>>1).
// 128x128 tile, BK=64, 4 waves (2x2), 4x4 16x16x32 frags per wave.
// 1D grid + bijective XCD swizzle (m204) for per-XCD L2 locality.

__global__ __launch_bounds__(256) void k_gemm(
    const bf16* __restrict__ A, const bf16* __restrict__ BT,
    float* __restrict__ C, int KA, int K2, int ldc, int gx) {
    const int nwg = gridDim.x;
    const int wg  = blockIdx.x;
    const int q = nwg >> 3, r = nwg & 7;
    const int xcd = wg & 7, idx0 = wg >> 3;
    const int swz = (xcd < r ? xcd * (q + 1) : r * (q + 1) + (xcd - r) * q) + idx0;
    const int m0 = (swz % gx) * 128;
    const int n0 = (swz / gx) * 128;
    __shared__ __align__(16) short Alds[128 * 64];
    __shared__ __align__(16) short Blds[128 * 64];
    const int tid  = threadIdx.x;
    const int lane = tid & 63;
    const int wave = tid >> 6;
    const int wbase = wave * 64;          // lane-uniform within wave
    const int wm = (wave >> 1) * 64;
    const int wn = (wave & 1) * 64;
    const int r16 = lane & 15;
    const int kg  = lane >> 4;
    f32x4 acc[4][4] = {};
    const int nkt = K2 >> 6;
    for (int kt = 0; kt < nkt; ++kt) {
        const int kB0 = kt << 6;
        const int kA0 = (kt >> 1) << 6;
        __syncthreads();
        // stage tiles: 1024 x 16B each; global_load_lds, 16B/lane
#pragma unroll
        for (int rr = 0; rr < 4; ++rr) {
            int idx = rr * 256 + wbase + lane;   // 16B unit within tile
            int row = idx >> 3;
            int c8  = (idx & 7) << 3;
            if ((kt & 1) == 0)
                __builtin_amdgcn_global_load_lds(
                    ASG(&A[(size_t)(m0 + row) * KA + kA0 + c8]),
                    ASL(&Alds[(rr * 256 + wbase) * 8]), 16, 0, 0);
            __builtin_amdgcn_global_load_lds(
                ASG(&BT[(size_t)(n0 + row) * K2 + kB0 + c8]),
                ASL(&Blds[(rr * 256 + wbase) * 8]), 16, 0, 0);
        }
        __syncthreads();
#pragma unroll
        for (int kk = 0; kk < 2; ++kk) {
            bf16x8 af[4], bfr[4];
#pragma unroll
            for (int i = 0; i < 4; ++i) {
                af[i]  = *(const bf16x8*)&Alds[(wm + i * 16 + r16) * 64 + kk * 32 + kg * 8];
                bfr[i] = *(const bf16x8*)&Blds[(wn + i * 16 + r16) * 64 + kk * 32 + kg * 8];
            }
#pragma unroll
            for (int mi = 0; mi < 4; ++mi)
#pragma unroll
                for (int ni = 0; ni < 4; ++ni)
                    acc[mi][ni] = __builtin_amdgcn_mfma_f32_16x16x32_bf16(
                        af[mi], bfr[ni], acc[mi][ni], 0, 0, 0);
        }
    }
    // epilogue: D row = kg*4 + r, col = r16 (m89 mapping); store cols < ldc
#pragma unroll
    for (int mi = 0; mi < 4; ++mi)
#pragma unroll
        for (int ni = 0; ni < 4; ++ni) {
            int col = n0 + wn + ni * 16 + r16;
            if (col < ldc) {
#pragma unroll
                for (int rr = 0; rr < 4; ++rr) {
                    int row = m0 + wm + mi * 16 + kg * 4 + rr;
                    C[(size_t)row * ldc + col] = acc[mi][ni][rr];
                }
            }
        }
}

// ---------------- LIF scan kernels (fp64 membranes) ----------------

#define LIF_STEP(OFF, V)                                        \
    {                                                           \
        m = beta * m + (double)((V) + bj);                      \
        bool sp = (m >= 1.0);                                   \
        S[OFF] = sp ? one : zero;                               \
        m = sp ? 0.0 : m;                                       \
    }

// hidden layer: 16384 chains, 64-thread blocks (1 wave) x 256 blocks.
// TLP (256 blocks) hides load latency here; register prefetch is best-effort.
__global__ __launch_bounds__(64) void k_scan_hidden(
    const float* __restrict__ I, const float* __restrict__ bias,
    double* __restrict__ mstate, bf16* __restrict__ S, int Tc, double beta) {
    int gid = blockIdx.x * 64 + threadIdx.x;
    int j = gid & (NH - 1);
    double m = mstate[gid];
    float bj = bias[j];
    const bf16 one  = __float2bfloat16(1.0f);
    const bf16 zero = __float2bfloat16(0.0f);
    const size_t stride = (size_t)NB * NH;       // per-t stride
    const float* Ip = I + gid;                   // gid = b*NH + j
    float bufA[8], bufB[8];
#pragma unroll
    for (int u = 0; u < 8; ++u) bufA[u] = Ip[(size_t)u * stride];
    for (int tb = 0; tb < Tc; tb += 16) {
#pragma unroll
        for (int u = 0; u < 8; ++u) bufB[u] = Ip[(size_t)(tb + 8 + u) * stride];
#pragma unroll
        for (int u = 0; u < 8; ++u) {
            size_t off = (size_t)(tb + u) * stride + gid;
            LIF_STEP(off, bufA[u]);
        }
        if (tb + 16 < Tc) {
#pragma unroll
            for (int u = 0; u < 8; ++u) bufA[u] = Ip[(size_t)(tb + 16 + u) * stride];
        }
#pragma unroll
        for (int u = 0; u < 8; ++u) {
            size_t off = (size_t)(tb + 8 + u) * stride + gid;
            LIF_STEP(off, bufB[u]);
        }
    }
    mstate[gid] = m;
}

// output layer: 256 chains (160 live), compact I2 [Tc x 256].
// One block, 4 waves. Wave w owns columns [64w, 64w+64): it stages its own
// columns via global_load_lds (no VGPR pipeline -> compiler cannot collapse)
// into a double-buffered LDS segment, processes the previous segment, then
// vmcnt(0). No cross-wave dependency, no barriers.
__global__ __launch_bounds__(256) void k_scan_out(
    const float* __restrict__ I2, const float* __restrict__ bias,
    double* __restrict__ mstate, float* __restrict__ out,
    int Tc, int t0, double beta) {
    __shared__ __align__(16) float seg[2][SEG * 256];
    const int tid  = threadIdx.x;
    const int lane = tid & 63;
    const int wave = tid >> 6;
    const int k = tid & 15;
    const int b = tid >> 4;
    double m = mstate[tid];
    float bj = (k < N_OUT) ? bias[k] : 0.f;
    const int nseg = (Tc + SEG - 1) / SEG;
    // preload segment 0 (this wave's 64 columns, one 4B glds per row)
    {
        int rows = (Tc < SEG) ? Tc : SEG;
        for (int rr = 0; rr < rows; ++rr)
            __builtin_amdgcn_global_load_lds(
                ASG(I2 + (size_t)rr * 256 + wave * 64 + lane),
                ASL(&seg[0][rr * 256 + wave * 64]), 4, 0, 0);
    }
    for (int s = 0; s < nseg; ++s) {
        asm volatile("s_waitcnt vmcnt(0)" ::: "memory");   // seg s resident
        __builtin_amdgcn_sched_barrier(0);
        // issue prefetch for segment s+1
        if (s + 1 < nseg) {
            int bt = (s + 1) * SEG;
            int rows = (Tc - bt < SEG) ? (Tc - bt) : SEG;
            for (int rr = 0; rr < rows; ++rr)
                __builtin_amdgcn_global_load_lds(
                    ASG(I2 + ((size_t)bt + rr) * 256 + wave * 64 + lane),
                    ASL(&seg[(s + 1) & 1][rr * 256 + wave * 64]), 4, 0, 0);
        }
        __builtin_amdgcn_sched_barrier(0);
        // process segment s from LDS
        int bt = s * SEG;
        int rows = (Tc - bt < SEG) ? (Tc - bt) : SEG;
        const float* sp_lds = &seg[s & 1][0];
        for (int rr = 0; rr < rows; ++rr) {
            float Iv = sp_lds[rr * 256 + tid];
            m = beta * m + (double)(Iv + bj);
            bool sp = (m >= 1.0);
            if (k < N_OUT)
                out[((size_t)(t0 + bt + rr) * NB + b) * N_OUT + k] = sp ? 1.f : 0.f;
            m = sp ? 0.0 : m;
        }
        __builtin_amdgcn_sched_barrier(0);
    }
    mstate[tid] = m;
}

// ---------------- host ----------------

extern "C" void kernel_launch(void* const* d_in, const int* in_sizes, int n_in,
                              void* d_out, int out_size, void* d_ws, size_t ws_size,
                              hipStream_t stream) {
    const float* in_sp = (const float*)d_in[0];
    const float* W0 = (const float*)d_in[1];
    const float* b0 = (const float*)d_in[2];
    const float* W1 = (const float*)d_in[3];
    const float* b1 = (const float*)d_in[4];
    const float* W2 = (const float*)d_in[5];
    const float* b2 = (const float*)d_in[6];
    float* out = (float*)d_out;

    char* p = (char*)d_ws;
    auto carve = [&](size_t bytes) -> void* {
        char* r = p; p += (bytes + 255) & ~(size_t)255; return (void*)r;
    };
    bf16* A_in = (bf16*)carve((size_t)T_STEPS * NB * N_IN * 2);
    bf16* BT0  = (bf16*)carve((size_t)NH * 2 * N_IN * 2);
    bf16* BT1  = (bf16*)carve((size_t)NH * 2 * NH * 2);
    bf16* BT2  = (bf16*)carve((size_t)128 * 2 * NH * 2);
    double* m0s = (double*)carve((size_t)NB * NH * 8);
    double* m1s = (double*)carve((size_t)NB * NH * 8);
    double* m2s = (double*)carve((size_t)NB * 16 * 8);
    size_t fixed = (size_t)(p - (char*)d_ws);

    // time-chunk: Tc | 4000, Tc % 16 == 0 (scan_hidden pipeline), Mc % 128 == 0
    const int tc_opts[7] = {2000, 800, 400, 160, 80, 32, 16};
    int Tc = 16;
    for (int i = 0; i < 7; ++i) {
        size_t Mc_ = (size_t)tc_opts[i] * NB;
        size_t need = fixed
            + ((Mc_ * NH * 4 + 255) & ~(size_t)255)
            + ((Mc_ * 16 * 4 + 255) & ~(size_t)255)
            + ((Mc_ * NH * 2 + 255) & ~(size_t)255);
        if (need <= ws_size) { Tc = tc_opts[i]; break; }
    }
    size_t Mc = (size_t)Tc * NB;
    float* IBUF  = (float*)carve(Mc * NH * 4);
    float* I2BUF = (float*)carve(Mc * 16 * 4);
    bf16*  S     = (bf16*)carve(Mc * NH * 2);

    const double beta = exp(-0.25 / 10.0);

    int nM = NB * NH;
    k_zero<<<(nM + 255) / 256, 256, 0, stream>>>(m0s, nM);
    k_zero<<<(nM + 255) / 256, 256, 0, stream>>>(m1s, nM);
    k_zero<<<1, 256, 0, stream>>>(m2s, NB * 16);

    int nIn = T_STEPS * NB * N_IN;
    k_cvt<<<(nIn + 255) / 256, 256, 0, stream>>>(in_sp, A_in, nIn);

    k_limbs<<<(NH * 2 * N_IN + 255) / 256, 256, 0, stream>>>(W0, BT0, N_IN, NH, NH);
    k_limbs<<<(NH * 2 * NH + 255) / 256, 256, 0, stream>>>(W1, BT1, NH, NH, NH);
    k_limbs<<<(128 * 2 * NH + 255) / 256, 256, 0, stream>>>(W2, BT2, NH, N_OUT, 128);

    const int C = T_STEPS / Tc;
    const int gx = (int)(Mc / 128);
    for (int c = 0; c < C; ++c) {
        int t0 = c * Tc;
        const bf16* Ain_c = A_in + (size_t)t0 * NB * N_IN;
        // layer 0
        k_gemm<<<gx * 8, 256, 0, stream>>>(Ain_c, BT0, IBUF, N_IN, 2 * N_IN, NH, gx);
        k_scan_hidden<<<(NB * NH) / 64, 64, 0, stream>>>(IBUF, b0, m0s, S, Tc, beta);
        // layer 1
        k_gemm<<<gx * 8, 256, 0, stream>>>(S, BT1, IBUF, NH, 2 * NH, NH, gx);
        k_scan_hidden<<<(NB * NH) / 64, 64, 0, stream>>>(IBUF, b1, m1s, S, Tc, beta);
        // layer 2 (compact 16-col C)
        k_gemm<<<gx, 256, 0, stream>>>(S, BT2, I2BUF, NH, 2 * NH, 16, gx);
        k_scan_out<<<1, 256, 0, stream>>>(I2BUF, b2, m2s, out, Tc, t0, beta);
    }
}

// Round 5
// 1031.889 us; speedup vs baseline: 1.1380x; 1.1380x over previous
//
#include <hip/hip_runtime.h>
#include <hip/hip_bf16.h>
#include <math.h>

// SNN forward: 64 -> 1024 -> 1024 -> 10, T=4000, B=16, LIF beta=exp(-0.025),
// thr=1, hard reset to 0, Dale clamp W>=0.
// Layer-phased: per time-chunk, GEMM (spikes @ W bf16-limbs, fp32 acc) ->
// LIF scan (fp64 membranes). Spikes as bf16 {0,1}.
// k_scan_out (R4 postmortem): single runtime-indexed LDS dbuf + runtime-bound
// row loop let the compiler serialize one VMEM round-trip per step (~590 cy).
// Fix: statically distinct segA/segB + x2-unrolled segment loop + 8-step
// compile-time-unrolled processing (batched ds_reads, batched stores).

#define T_STEPS 4000
#define NB 16
#define N_IN 64
#define NH 1024
#define N_OUT 10
#define SEG 40            // scan_out segment rows; 2 x 40KB LDS

typedef __attribute__((ext_vector_type(8))) short bf16x8;
typedef __attribute__((ext_vector_type(4))) float f32x4;
typedef __hip_bfloat16 bf16;

#define ASG(p) (const __attribute__((address_space(1))) void*)(p)
#define ASL(p) (__attribute__((address_space(3))) void*)(p)

// ---------------- small utility kernels ----------------

__global__ void k_zero(double* p, int n) {
    int i = blockIdx.x * 256 + threadIdx.x;
    if (i < n) p[i] = 0.0;
}

__global__ void k_cvt(const float* __restrict__ in, bf16* __restrict__ out, int n) {
    int i = blockIdx.x * 256 + threadIdx.x;
    if (i < n) out[i] = __float2bfloat16(in[i]);   // 0.0/1.0 -> exact
}

// Build BT[n][k2] (row-major [Npad x 2K]) from W [K x N] row-major.
// Limb-interleaved K2: k2 -> kt2 = k2>>6, kk = k2&63; limb = kt2&1,
// source k = (kt2>>1)*64 + kk. limb0 = hi(max(W,0)), limb1 = w - hi.
__global__ void k_limbs(const float* __restrict__ W, bf16* __restrict__ BT,
                        int K, int N, int Npad) {
    int idx = blockIdx.x * 256 + threadIdx.x;
    int total = Npad * 2 * K;
    if (idx >= total) return;
    int n  = idx / (2 * K);
    int k2 = idx - n * (2 * K);
    int kt2 = k2 >> 6;
    int kk  = k2 & 63;
    int k   = ((kt2 >> 1) << 6) + kk;
    float v = 0.f;
    if (n < N) {
        float w = fmaxf(W[(size_t)k * N + n], 0.f);      // Dale's law clamp
        float hi = __bfloat162float(__float2bfloat16(w));
        v = ((kt2 & 1) == 0) ? w : (w - hi);
    }
    BT[idx] = __float2bfloat16(v);
}

// ---------------- GEMM: C[M x ldc] = A[M x KA] @ BT^T, bf16 in, f32 out ----
// BT is [Npad x K2], limb-interleaved: k-iteration kt uses A k-tile (kt>>1).
// 128x128 tile, BK=64, 4 waves (2x2), 4x4 16x16x32 frags per wave.
// 1D grid + bijective XCD swizzle (m204) for per-XCD L2 locality.

__global__ __launch_bounds__(256) void k_gemm(
    const bf16* __restrict__ A, const bf16* __restrict__ BT,
    float* __restrict__ C, int KA, int K2, int ldc, int gx) {
    const int nwg = gridDim.x;
    const int wg  = blockIdx.x;
    const int q = nwg >> 3, r = nwg & 7;
    const int xcd = wg & 7, idx0 = wg >> 3;
    const int swz = (xcd < r ? xcd * (q + 1) : r * (q + 1) + (xcd - r) * q) + idx0;
    const int m0 = (swz % gx) * 128;
    const int n0 = (swz / gx) * 128;
    __shared__ __align__(16) short Alds[128 * 64];
    __shared__ __align__(16) short Blds[128 * 64];
    const int tid  = threadIdx.x;
    const int lane = tid & 63;
    const int wave = tid >> 6;
    const int wbase = wave * 64;          // lane-uniform within wave
    const int wm = (wave >> 1) * 64;
    const int wn = (wave & 1) * 64;
    const int r16 = lane & 15;
    const int kg  = lane >> 4;
    f32x4 acc[4][4] = {};
    const int nkt = K2 >> 6;
    for (int kt = 0; kt < nkt; ++kt) {
        const int kB0 = kt << 6;
        const int kA0 = (kt >> 1) << 6;
        __syncthreads();
        // stage tiles: 1024 x 16B each; global_load_lds, 16B/lane
#pragma unroll
        for (int rr = 0; rr < 4; ++rr) {
            int idx = rr * 256 + wbase + lane;   // 16B unit within tile
            int row = idx >> 3;
            int c8  = (idx & 7) << 3;
            if ((kt & 1) == 0)
                __builtin_amdgcn_global_load_lds(
                    ASG(&A[(size_t)(m0 + row) * KA + kA0 + c8]),
                    ASL(&Alds[(rr * 256 + wbase) * 8]), 16, 0, 0);
            __builtin_amdgcn_global_load_lds(
                ASG(&BT[(size_t)(n0 + row) * K2 + kB0 + c8]),
                ASL(&Blds[(rr * 256 + wbase) * 8]), 16, 0, 0);
        }
        __syncthreads();
#pragma unroll
        for (int kk = 0; kk < 2; ++kk) {
            bf16x8 af[4], bfr[4];
#pragma unroll
            for (int i = 0; i < 4; ++i) {
                af[i]  = *(const bf16x8*)&Alds[(wm + i * 16 + r16) * 64 + kk * 32 + kg * 8];
                bfr[i] = *(const bf16x8*)&Blds[(wn + i * 16 + r16) * 64 + kk * 32 + kg * 8];
            }
#pragma unroll
            for (int mi = 0; mi < 4; ++mi)
#pragma unroll
                for (int ni = 0; ni < 4; ++ni)
                    acc[mi][ni] = __builtin_amdgcn_mfma_f32_16x16x32_bf16(
                        af[mi], bfr[ni], acc[mi][ni], 0, 0, 0);
        }
    }
    // epilogue: D row = kg*4 + r, col = r16 (m89 mapping); store cols < ldc
#pragma unroll
    for (int mi = 0; mi < 4; ++mi)
#pragma unroll
        for (int ni = 0; ni < 4; ++ni) {
            int col = n0 + wn + ni * 16 + r16;
            if (col < ldc) {
#pragma unroll
                for (int rr = 0; rr < 4; ++rr) {
                    int row = m0 + wm + mi * 16 + kg * 4 + rr;
                    C[(size_t)row * ldc + col] = acc[mi][ni][rr];
                }
            }
        }
}

// ---------------- LIF scan kernels (fp64 membranes) ----------------

// hidden layer: 16384 chains, 64-thread blocks (1 wave) x 256 blocks.
__global__ __launch_bounds__(64) void k_scan_hidden(
    const float* __restrict__ I, const float* __restrict__ bias,
    double* __restrict__ mstate, bf16* __restrict__ S, int Tc, double beta) {
    int gid = blockIdx.x * 64 + threadIdx.x;
    int j = gid & (NH - 1);
    double m = mstate[gid];
    float bj = bias[j];
    const bf16 one  = __float2bfloat16(1.0f);
    const bf16 zero = __float2bfloat16(0.0f);
    const size_t stride = (size_t)NB * NH;       // per-t stride
    const float* Ip = I + gid;                   // gid = b*NH + j
    float bufA[8], bufB[8];
#pragma unroll
    for (int u = 0; u < 8; ++u) bufA[u] = Ip[(size_t)u * stride];
    for (int tb = 0; tb < Tc; tb += 16) {
#pragma unroll
        for (int u = 0; u < 8; ++u) bufB[u] = Ip[(size_t)(tb + 8 + u) * stride];
#pragma unroll
        for (int u = 0; u < 8; ++u) {
            size_t off = (size_t)(tb + u) * stride + gid;
            m = beta * m + (double)(bufA[u] + bj);
            bool sp = (m >= 1.0);
            S[off] = sp ? one : zero;
            m = sp ? 0.0 : m;
        }
        if (tb + 16 < Tc) {
#pragma unroll
            for (int u = 0; u < 8; ++u) bufA[u] = Ip[(size_t)(tb + 16 + u) * stride];
        }
#pragma unroll
        for (int u = 0; u < 8; ++u) {
            size_t off = (size_t)(tb + 8 + u) * stride + gid;
            m = beta * m + (double)(bufB[u] + bj);
            bool sp = (m >= 1.0);
            S[off] = sp ? one : zero;
            m = sp ? 0.0 : m;
        }
    }
    mstate[gid] = m;
}

// output layer: 256 chains (160 live), compact I2 [Tc x 256].
// One block, 4 waves; wave w stages its own 64 columns via global_load_lds
// into statically-distinct segA/segB (x2-unrolled segment loop -> no runtime
// LDS indexing, no alias-driven waits). Processing is 8-step unrolled:
// batched ds_reads -> serial fp64 chain -> batched stores.
__global__ __launch_bounds__(256) void k_scan_out(
    const float* __restrict__ I2, const float* __restrict__ bias,
    double* __restrict__ mstate, float* __restrict__ out,
    int Tc, int t0, double beta) {
    __shared__ __align__(16) float segA[SEG * 256];
    __shared__ __align__(16) float segB[SEG * 256];
    const int tid  = threadIdx.x;
    const int lane = tid & 63;
    const int wave = tid >> 6;
    const int k = tid & 15;
    const int b = tid >> 4;
    double m = mstate[tid];
    float bj = (k < N_OUT) ? bias[k] : 0.f;
    const int nseg = Tc / SEG;                   // Tc % (2*SEG) == 0 by host

#define PREFETCH(SEGBUF, SIDX)                                              \
    {                                                                       \
        const float* src = I2 + (size_t)(SIDX) * SEG * 256 + wave * 64 + lane; \
        _Pragma("unroll 8")                                                 \
        for (int rr = 0; rr < SEG; ++rr)                                    \
            __builtin_amdgcn_global_load_lds(                               \
                ASG(src + (size_t)rr * 256),                                \
                ASL(&SEGBUF[rr * 256 + wave * 64]), 4, 0, 0);               \
    }

#define PROC_SEG(SEGBUF, SIDX)                                              \
    {                                                                       \
        const int btt = (SIDX) * SEG;                                       \
        _Pragma("unroll")                                                   \
        for (int sb = 0; sb < SEG / 8; ++sb) {                              \
            float v[8];                                                     \
            _Pragma("unroll")                                               \
            for (int u = 0; u < 8; ++u)                                     \
                v[u] = SEGBUF[(sb * 8 + u) * 256 + tid];                    \
            float o[8];                                                     \
            _Pragma("unroll")                                               \
            for (int u = 0; u < 8; ++u) {                                   \
                m = beta * m + (double)(v[u] + bj);                         \
                bool sp = (m >= 1.0);                                       \
                o[u] = sp ? 1.f : 0.f;                                      \
                m = sp ? 0.0 : m;                                           \
            }                                                               \
            if (k < N_OUT) {                                                \
                _Pragma("unroll")                                           \
                for (int u = 0; u < 8; ++u)                                 \
                    out[((size_t)(t0 + btt + sb * 8 + u) * NB + b) * N_OUT + k] = o[u]; \
            }                                                               \
        }                                                                   \
    }

    PREFETCH(segA, 0);
    for (int s = 0; s < nseg; s += 2) {
        asm volatile("s_waitcnt vmcnt(0)" ::: "memory");   // segA resident
        __builtin_amdgcn_sched_barrier(0);
        PREFETCH(segB, s + 1);
        __builtin_amdgcn_sched_barrier(0);
        PROC_SEG(segA, s);
        asm volatile("s_waitcnt vmcnt(0)" ::: "memory");   // segB resident
        __builtin_amdgcn_sched_barrier(0);
        if (s + 2 < nseg) PREFETCH(segA, s + 2);
        __builtin_amdgcn_sched_barrier(0);
        PROC_SEG(segB, s + 1);
    }
    mstate[tid] = m;
#undef PREFETCH
#undef PROC_SEG
}

// ---------------- host ----------------

extern "C" void kernel_launch(void* const* d_in, const int* in_sizes, int n_in,
                              void* d_out, int out_size, void* d_ws, size_t ws_size,
                              hipStream_t stream) {
    const float* in_sp = (const float*)d_in[0];
    const float* W0 = (const float*)d_in[1];
    const float* b0 = (const float*)d_in[2];
    const float* W1 = (const float*)d_in[3];
    const float* b1 = (const float*)d_in[4];
    const float* W2 = (const float*)d_in[5];
    const float* b2 = (const float*)d_in[6];
    float* out = (float*)d_out;

    char* p = (char*)d_ws;
    auto carve = [&](size_t bytes) -> void* {
        char* r = p; p += (bytes + 255) & ~(size_t)255; return (void*)r;
    };
    bf16* A_in = (bf16*)carve((size_t)T_STEPS * NB * N_IN * 2);
    bf16* BT0  = (bf16*)carve((size_t)NH * 2 * N_IN * 2);
    bf16* BT1  = (bf16*)carve((size_t)NH * 2 * NH * 2);
    bf16* BT2  = (bf16*)carve((size_t)128 * 2 * NH * 2);
    double* m0s = (double*)carve((size_t)NB * NH * 8);
    double* m1s = (double*)carve((size_t)NB * NH * 8);
    double* m2s = (double*)carve((size_t)NB * 16 * 8);
    size_t fixed = (size_t)(p - (char*)d_ws);

    // Tc | 4000, Tc % 80 == 0 (scan_out needs even nseg of 40), Mc % 128 == 0
    const int tc_opts[5] = {2000, 800, 400, 160, 80};
    int Tc = 80;
    for (int i = 0; i < 5; ++i) {
        size_t Mc_ = (size_t)tc_opts[i] * NB;
        size_t need = fixed
            + ((Mc_ * NH * 4 + 255) & ~(size_t)255)
            + ((Mc_ * 16 * 4 + 255) & ~(size_t)255)
            + ((Mc_ * NH * 2 + 255) & ~(size_t)255);
        if (need <= ws_size) { Tc = tc_opts[i]; break; }
    }
    size_t Mc = (size_t)Tc * NB;
    float* IBUF  = (float*)carve(Mc * NH * 4);
    float* I2BUF = (float*)carve(Mc * 16 * 4);
    bf16*  S     = (bf16*)carve(Mc * NH * 2);

    const double beta = exp(-0.25 / 10.0);

    int nM = NB * NH;
    k_zero<<<(nM + 255) / 256, 256, 0, stream>>>(m0s, nM);
    k_zero<<<(nM + 255) / 256, 256, 0, stream>>>(m1s, nM);
    k_zero<<<1, 256, 0, stream>>>(m2s, NB * 16);

    int nIn = T_STEPS * NB * N_IN;
    k_cvt<<<(nIn + 255) / 256, 256, 0, stream>>>(in_sp, A_in, nIn);

    k_limbs<<<(NH * 2 * N_IN + 255) / 256, 256, 0, stream>>>(W0, BT0, N_IN, NH, NH);
    k_limbs<<<(NH * 2 * NH + 255) / 256, 256, 0, stream>>>(W1, BT1, NH, NH, NH);
    k_limbs<<<(128 * 2 * NH + 255) / 256, 256, 0, stream>>>(W2, BT2, NH, N_OUT, 128);

    const int C = T_STEPS / Tc;
    const int gx = (int)(Mc / 128);
    for (int c = 0; c < C; ++c) {
        int t0 = c * Tc;
        const bf16* Ain_c = A_in + (size_t)t0 * NB * N_IN;
        // layer 0
        k_gemm<<<gx * 8, 256, 0, stream>>>(Ain_c, BT0, IBUF, N_IN, 2 * N_IN, NH, gx);
        k_scan_hidden<<<(NB * NH) / 64, 64, 0, stream>>>(IBUF, b0, m0s, S, Tc, beta);
        // layer 1
        k_gemm<<<gx * 8, 256, 0, stream>>>(S, BT1, IBUF, NH, 2 * NH, NH, gx);
        k_scan_hidden<<<(NB * NH) / 64, 64, 0, stream>>>(IBUF, b1, m1s, S, Tc, beta);
        // layer 2 (compact 16-col C)
        k_gemm<<<gx, 256, 0, stream>>>(S, BT2, I2BUF, NH, 2 * NH, 16, gx);
        k_scan_out<<<1, 256, 0, stream>>>(I2BUF, b2, m2s, out, Tc, t0, beta);
    }
}